// Round 6
// baseline (1891.910 us; speedup 1.0000x reference)
//
#include <hip/hip_runtime.h>

#define M_DIM 8192
#define K_DIM 4096
#define N_DIM 11008
#define BM 128
#define BN 256
#define BK 64
#define TILES_M (M_DIM / BM)     // 64
#define TILES_N (N_DIM / BN)     // 43
#define NT (K_DIM / BK)          // 64
#define NWG (TILES_M * TILES_N)  // 2752 = 8 * 344

typedef __attribute__((ext_vector_type(8))) short bf16x8;
typedef __attribute__((ext_vector_type(4))) float f32x4;
typedef __attribute__((ext_vector_type(8))) unsigned short u16x8;

__device__ __forceinline__ unsigned short f2bf_rne(float f) {
    unsigned int u = __float_as_uint(f);
    unsigned int r = (u + 0x7FFFu + ((u >> 16) & 1u)) >> 16;
    return (unsigned short)r;
}

__device__ __forceinline__ void gload_lds16(const void* g, void* l) {
    __builtin_amdgcn_global_load_lds(
        (const __attribute__((address_space(1))) void*)g,
        (__attribute__((address_space(3))) void*)l, 16, 0, 0);
}

// ---------------- x: fp32 -> bf16 (8 elems / thread) ----------------
__global__ __launch_bounds__(256) void cast_x_kernel(const float* __restrict__ x,
                                                     unsigned short* __restrict__ xb) {
    size_t t = (size_t)blockIdx.x * 256 + threadIdx.x;
    const float4* p = reinterpret_cast<const float4*>(x) + 2 * t;
    float4 a = p[0];
    float4 b = p[1];
    u16x8 o;
    o[0] = f2bf_rne(a.x); o[1] = f2bf_rne(a.y); o[2] = f2bf_rne(a.z); o[3] = f2bf_rne(a.w);
    o[4] = f2bf_rne(b.x); o[5] = f2bf_rne(b.y); o[6] = f2bf_rne(b.z); o[7] = f2bf_rne(b.w);
    *reinterpret_cast<u16x8*>(xb + 8 * t) = o;
}

// ------- weight: per-128-group absmax scale, sign*scale -> bf16 -------
__global__ __launch_bounds__(256) void binarize_w_kernel(const float* __restrict__ w,
                                                         unsigned short* __restrict__ weff) {
    size_t t = (size_t)blockIdx.x * 256 + threadIdx.x;
    size_t group = t >> 5;
    int l32 = (int)(t & 31);
    const float4* src = reinterpret_cast<const float4*>(w + group * 128) + l32;
    float4 v = *src;
    float amax = fmaxf(fmaxf(fabsf(v.x), fabsf(v.y)), fmaxf(fabsf(v.z), fabsf(v.w)));
#pragma unroll
    for (int off = 16; off >= 1; off >>= 1)
        amax = fmaxf(amax, __shfl_xor(amax, off));
    float scale = fmaxf(amax, 1e-8f);
    unsigned short pb = f2bf_rne(scale);
    unsigned short nb = (unsigned short)(pb | 0x8000u);
    ushort4 o;
    o.x = (v.x == 0.0f) ? (unsigned short)0 : ((v.x > 0.0f) ? pb : nb);
    o.y = (v.y == 0.0f) ? (unsigned short)0 : ((v.y > 0.0f) ? pb : nb);
    o.z = (v.z == 0.0f) ? (unsigned short)0 : ((v.z > 0.0f) ? pb : nb);
    o.w = (v.w == 0.0f) ? (unsigned short)0 : ((v.w > 0.0f) ? pb : nb);
    *reinterpret_cast<ushort4*>(weff + group * 128 + (size_t)l32 * 4) = o;
}

// ---------------- GEMM: C[M][N] = Xb[M][K] * Weff[N][K]^T ----------------
// 128x256 tile, BK=64, 4 waves (1Mx4N). A via LDS (32 KiB double-buffered,
// XOR-swizzled); B DIRECT global->register (lane-native fragments, one 16B
// load each, full-cacheline consumption, L2-served). 2 blocks/CU. One
// barrier + one vmcnt(0) per K-tile; all loads issued a full tile ahead.
__global__ __launch_bounds__(256, 2) void gemm_bin_kernel(
        const unsigned short* __restrict__ A,   // Xb  [M][K] bf16
        const unsigned short* __restrict__ B,   // Weff[N][K] bf16
        float* __restrict__ C) {
    __shared__ unsigned short As[2][BM * BK];   // 2 x 16 KiB

    const int bid = blockIdx.x;
    const int swz = (bid & 7) * (NWG / 8) + (bid >> 3);   // bijective: NWG % 8 == 0
    const int tm = swz / TILES_N;
    const int tn = swz % TILES_N;

    const int tid = threadIdx.x;
    const int wave = tid >> 6;     // 0..3 -> B col block
    const int lane = tid & 63;
    const int l15 = lane & 15;
    const int l4  = lane >> 4;

    // ---- A staging: linear LDS dest, pre-swizzled global source ----
    const int srow  = tid >> 3;                  // 0..31 (chunk adds +32)
    const int gslot = (tid & 7) ^ (srow & 7);    // 32 % 8 == 0 -> chunk-invariant
    const unsigned short* Asrc = A + (size_t)(tm * BM + srow) * K_DIM + gslot * 8;

    auto stageA = [&](int buf, int kt) {
#pragma unroll
        for (int cc = 0; cc < 4; ++cc)
            gload_lds16(Asrc + (size_t)(cc * 32) * K_DIM + kt,
                        &As[buf][cc * 2048 + tid * 8]);
    };
    auto readA = [&](int buf, int i, int ks) -> bf16x8 {
        int row = i * 16 + l15;
        return *reinterpret_cast<const bf16x8*>(
            &As[buf][row * 64 + (((ks * 4 + l4) ^ (row & 7)) * 8)]);
    };

    // ---- B direct-to-register fragment pointers ----
    const unsigned short* Bp[4];
#pragma unroll
    for (int j = 0; j < 4; ++j)
        Bp[j] = B + (size_t)(tn * BN + wave * 64 + j * 16 + l15) * K_DIM + l4 * 8;

    f32x4 acc[8][4] = {};
    bf16x8 b0[4][2], b1[4][2], af0[4], af1[4];

#define LOAD_B(BANK, KT)                                                        \
    { _Pragma("unroll") for (int j_ = 0; j_ < 4; ++j_) {                        \
        BANK[j_][0] = *reinterpret_cast<const bf16x8*>(Bp[j_] + (KT));          \
        BANK[j_][1] = *reinterpret_cast<const bf16x8*>(Bp[j_] + (KT) + 32); } }
#define READ_A4(DST, BUF, H, KS)                                                \
    { _Pragma("unroll") for (int r_ = 0; r_ < 4; ++r_)                          \
        DST[r_] = readA(BUF, (H) * 4 + r_, KS); }
#define MFMA16(AF, BANK, H, KS)                                                 \
    { _Pragma("unroll") for (int r_ = 0; r_ < 4; ++r_) {                        \
        _Pragma("unroll") for (int j_ = 0; j_ < 4; ++j_)                        \
            acc[(H) * 4 + r_][j_] = __builtin_amdgcn_mfma_f32_16x16x32_bf16(    \
                AF[r_], BANK[j_][KS], acc[(H) * 4 + r_][j_], 0, 0, 0); } }

    // ---- prologue ----
    stageA(0, 0);
    LOAD_B(b0, 0);
    asm volatile("s_waitcnt vmcnt(0)" ::: "memory");
    __builtin_amdgcn_s_barrier();

    // Per tile: issue A(t+1) stage + B(t+1) loads at top (pinned by
    // sched_barrier so they get a full tile of MFMA to land), compute
    // 64 MFMAs with A-frag reads interleaved, then vmcnt(0)+barrier.
#define KTILE(T, CUR, NXT, BC, BN_)                                             \
    {                                                                           \
        if ((T) + 1 < NT) {                                                     \
            stageA(NXT, ((T) + 1) * BK);                                        \
            LOAD_B(BN_, ((T) + 1) * BK);                                        \
            __builtin_amdgcn_sched_barrier(0);                                  \
        }                                                                       \
        READ_A4(af0, CUR, 0, 0);                                                \
        __builtin_amdgcn_s_setprio(1);                                          \
        READ_A4(af1, CUR, 1, 0);                                                \
        MFMA16(af0, BC, 0, 0);                                                  \
        READ_A4(af0, CUR, 0, 1);                                                \
        MFMA16(af1, BC, 1, 0);                                                  \
        READ_A4(af1, CUR, 1, 1);                                                \
        MFMA16(af0, BC, 0, 1);                                                  \
        MFMA16(af1, BC, 1, 1);                                                  \
        __builtin_amdgcn_s_setprio(0);                                          \
        if ((T) + 1 < NT) {                                                     \
            asm volatile("s_waitcnt vmcnt(0)" ::: "memory");                    \
            __builtin_amdgcn_s_barrier();                                       \
        }                                                                       \
    }

#pragma unroll 1
    for (int tt = 0; tt < NT; tt += 2) {
        KTILE(tt,     0, 1, b0, b1);
        KTILE(tt + 1, 1, 0, b1, b0);
    }

    // ---- epilogue: C/D layout col=lane&15, row=(lane>>4)*4+reg; NT stores ----
    const size_t crow0 = (size_t)tm * BM + l4 * 4;
    const int ccol0 = tn * BN + wave * 64 + l15;
#pragma unroll
    for (int i = 0; i < 8; ++i) {
#pragma unroll
        for (int j = 0; j < 4; ++j) {
            float* cp = C + (crow0 + i * 16) * N_DIM + ccol0 + j * 16;
#pragma unroll
            for (int r = 0; r < 4; ++r)
                __builtin_nontemporal_store(acc[i][j][r], cp + (size_t)r * N_DIM);
        }
    }
}

extern "C" void kernel_launch(void* const* d_in, const int* in_sizes, int n_in,
                              void* d_out, int out_size, void* d_ws, size_t ws_size,
                              hipStream_t stream) {
    const float* x = (const float*)d_in[0];       // [4,2048,4096] fp32
    const float* w = (const float*)d_in[1];       // [11008,4096] fp32
    float* out = (float*)d_out;                   // [4,2048,11008] fp32

    unsigned short* xb = (unsigned short*)d_ws;                                        // 64 MiB
    unsigned short* weff = (unsigned short*)((char*)d_ws + (size_t)M_DIM * K_DIM * 2); // 86 MiB

    cast_x_kernel<<<(M_DIM * K_DIM / 8) / 256, 256, 0, stream>>>(x, xb);
    binarize_w_kernel<<<(N_DIM * K_DIM / 4) / 256, 256, 0, stream>>>(w, weff);
    gemm_bin_kernel<<<NWG, 256, 0, stream>>>(xb, weff, out);
}

// Round 7
// 744.103 us; speedup vs baseline: 2.5425x; 2.5425x over previous
//
#include <hip/hip_runtime.h>

#define M_DIM 8192
#define K_DIM 4096
#define N_DIM 11008
#define BM 256
#define BN 256
#define BK 64
#define TILES_M (M_DIM / BM)     // 32
#define TILES_N (N_DIM / BN)     // 43
#define NT (K_DIM / BK)          // 64
#define NWG (TILES_M * TILES_N)  // 1376 = 8 * 172

typedef __attribute__((ext_vector_type(8))) short bf16x8;
typedef __attribute__((ext_vector_type(4))) float f32x4;
typedef __attribute__((ext_vector_type(8))) unsigned short u16x8;

__device__ __forceinline__ unsigned short f2bf_rne(float f) {
    unsigned int u = __float_as_uint(f);
    unsigned int r = (u + 0x7FFFu + ((u >> 16) & 1u)) >> 16;
    return (unsigned short)r;
}

__device__ __forceinline__ void gload_lds16(const void* g, void* l) {
    __builtin_amdgcn_global_load_lds(
        (const __attribute__((address_space(1))) void*)g,
        (__attribute__((address_space(3))) void*)l, 16, 0, 0);
}

// ---------------- x: fp32 -> bf16 (8 elems / thread) ----------------
__global__ __launch_bounds__(256) void cast_x_kernel(const float* __restrict__ x,
                                                     unsigned short* __restrict__ xb) {
    size_t t = (size_t)blockIdx.x * 256 + threadIdx.x;
    const float4* p = reinterpret_cast<const float4*>(x) + 2 * t;
    float4 a = p[0];
    float4 b = p[1];
    u16x8 o;
    o[0] = f2bf_rne(a.x); o[1] = f2bf_rne(a.y); o[2] = f2bf_rne(a.z); o[3] = f2bf_rne(a.w);
    o[4] = f2bf_rne(b.x); o[5] = f2bf_rne(b.y); o[6] = f2bf_rne(b.z); o[7] = f2bf_rne(b.w);
    *reinterpret_cast<u16x8*>(xb + 8 * t) = o;
}

// ------- weight: per-128-group absmax scale, sign*scale -> bf16 -------
__global__ __launch_bounds__(256) void binarize_w_kernel(const float* __restrict__ w,
                                                         unsigned short* __restrict__ weff) {
    size_t t = (size_t)blockIdx.x * 256 + threadIdx.x;
    size_t group = t >> 5;
    int l32 = (int)(t & 31);
    const float4* src = reinterpret_cast<const float4*>(w + group * 128) + l32;
    float4 v = *src;
    float amax = fmaxf(fmaxf(fabsf(v.x), fabsf(v.y)), fmaxf(fabsf(v.z), fabsf(v.w)));
#pragma unroll
    for (int off = 16; off >= 1; off >>= 1)
        amax = fmaxf(amax, __shfl_xor(amax, off));
    float scale = fmaxf(amax, 1e-8f);
    unsigned short pb = f2bf_rne(scale);
    unsigned short nb = (unsigned short)(pb | 0x8000u);
    ushort4 o;
    o.x = (v.x == 0.0f) ? (unsigned short)0 : ((v.x > 0.0f) ? pb : nb);
    o.y = (v.y == 0.0f) ? (unsigned short)0 : ((v.y > 0.0f) ? pb : nb);
    o.z = (v.z == 0.0f) ? (unsigned short)0 : ((v.z > 0.0f) ? pb : nb);
    o.w = (v.w == 0.0f) ? (unsigned short)0 : ((v.w > 0.0f) ? pb : nb);
    *reinterpret_cast<ushort4*>(weff + group * 128 + (size_t)l32 * 4) = o;
}

// ---------------- GEMM: C[M][N] = Xb[M][K] * Weff[N][K]^T ----------------
// Faithful 8-phase/2-K-tile template (m201 structure): per phase
// {in-phase ds_reads (12 at q0, 4 else); exactly 1 half-tile stage;
//  [lgkmcnt(8) if 12 reads]; barrier; lgkmcnt(0); setprio(1); 16 MFMA;
//  setprio(0); [vmcnt(4) at p3/p7]; barrier}.
// Stage placement (each right after its region's retire barrier):
//   A(t+1)->buf1 @p0,p1 | B(t+2)->buf0 @p2,p3 | A(t+2)->buf0 @p4,p5 |
//   B(t+3)->buf1 @p6,p7.  vmcnt ledger: 12 outstanding, oldest 8 needed.
__global__ __launch_bounds__(512, 2) void gemm_bin_kernel(
        const unsigned short* __restrict__ A,   // Xb  [M][K] bf16
        const unsigned short* __restrict__ B,   // Weff[N][K] bf16
        float* __restrict__ C) {
    __shared__ unsigned short lds[2][2][2][8192];  // [buf][A/B][half][128*64]

    const int bid = blockIdx.x;
    const int swz = (bid & 7) * (NWG / 8) + (bid >> 3);   // bijective: NWG % 8 == 0
    const int tm = swz / TILES_N;
    const int tn = swz % TILES_N;

    const int tid = threadIdx.x;
    const int wave = tid >> 6;
    const int lane = tid & 63;
    const int wm = wave >> 2;      // 0..1 -> A half
    const int wn = wave & 3;       // 0..3 -> B half = wn>>1, sub-block = wn&1
    const int l15 = lane & 15;
    const int l4  = lane >> 4;
    const int brow0 = (wn & 1) * 64;

    // ---- staging: linear LDS dest, pre-swizzled global source ----
    const int srow  = tid >> 3;                  // 0..63 (chunk adds +64)
    const int gslot = (tid & 7) ^ (srow & 7);
    const unsigned short* Asrc = A + (size_t)(tm * BM + srow) * K_DIM + gslot * 8;
    const unsigned short* Bsrc = B + (size_t)(tn * BN + srow) * K_DIM + gslot * 8;

    auto stageA = [&](int buf, int half, int kt) {
        const unsigned short* s = Asrc + (size_t)(half * 128) * K_DIM + kt;
        unsigned short* d = &lds[buf][0][half][tid * 8];
        gload_lds16(s, d);
        gload_lds16(s + (size_t)64 * K_DIM, d + 4096);
    };
    auto stageB = [&](int buf, int half, int kt) {
        const unsigned short* s = Bsrc + (size_t)(half * 128) * K_DIM + kt;
        unsigned short* d = &lds[buf][1][half][tid * 8];
        gload_lds16(s, d);
        gload_lds16(s + (size_t)64 * K_DIM, d + 4096);
    };
    auto readfrag = [&](const unsigned short* base, int rowl, int ks) -> bf16x8 {
        return *reinterpret_cast<const bf16x8*>(
            &base[rowl * 64 + (((ks * 4 + l4) ^ (rowl & 7)) * 8)]);
    };

    f32x4 acc[8][4] = {};
    bf16x8 bf[4][2], af[2][2];

#define READ_A(BASE, Q)                                                         \
    {                                                                           \
        _Pragma("unroll") for (int r_ = 0; r_ < 2; ++r_) {                      \
            _Pragma("unroll") for (int ks_ = 0; ks_ < 2; ++ks_) {               \
                af[r_][ks_] = readfrag(BASE, (2 * (Q) + r_) * 16 + l15, ks_);   \
            }                                                                   \
        }                                                                       \
    }
#define READ_B(BASE)                                                            \
    {                                                                           \
        _Pragma("unroll") for (int j_ = 0; j_ < 4; ++j_) {                      \
            _Pragma("unroll") for (int ks_ = 0; ks_ < 2; ++ks_) {               \
                bf[j_][ks_] = readfrag(BASE, brow0 + j_ * 16 + l15, ks_);       \
            }                                                                   \
        }                                                                       \
    }
#define MFMA_PH(Q)                                                              \
    {                                                                           \
        _Pragma("unroll") for (int ks_ = 0; ks_ < 2; ++ks_) {                   \
            _Pragma("unroll") for (int r_ = 0; r_ < 2; ++r_) {                  \
                _Pragma("unroll") for (int j_ = 0; j_ < 4; ++j_) {              \
                    acc[2 * (Q) + r_][j_] =                                     \
                        __builtin_amdgcn_mfma_f32_16x16x32_bf16(                \
                            af[r_][ks_], bf[j_][ks_], acc[2 * (Q) + r_][j_],    \
                            0, 0, 0);                                           \
                }                                                               \
            }                                                                   \
        }                                                                       \
    }
    // PHASE: reads -> stage -> [lgkm(8)] -> bar -> lgkm(0) -> prio MFMA -> [vm] -> bar
#define PHASE(ABASE, Q, RDB, BBASE, STAGE_STMT, VMSTMT)                         \
    {                                                                           \
        READ_A(ABASE, Q);                                                       \
        if (RDB) { READ_B(BBASE); }                                             \
        STAGE_STMT;                                                             \
        if (RDB) { asm volatile("s_waitcnt lgkmcnt(8)" ::: "memory"); }         \
        __builtin_amdgcn_s_barrier();                                           \
        asm volatile("s_waitcnt lgkmcnt(0)" ::: "memory");                      \
        __builtin_amdgcn_s_setprio(1);                                          \
        MFMA_PH(Q);                                                             \
        __builtin_amdgcn_s_setprio(0);                                          \
        VMSTMT;                                                                 \
        __builtin_amdgcn_s_barrier();                                           \
    }

    // ---- prologue: A(0),B(0)->buf0 (8 loads), B(1)->buf1 (4 loads) ----
    stageA(0, 0, 0); stageA(0, 1, 0);
    stageB(0, 0, 0); stageB(0, 1, 0);
    stageB(1, 0, BK); stageB(1, 1, BK);
    asm volatile("s_waitcnt vmcnt(4)" ::: "memory");   // A(0),B(0) done; B(1) in flight
    __builtin_amdgcn_s_barrier();

#pragma unroll 1
    for (int tt = 0; tt < NT; tt += 2) {
        const unsigned short* A0 = &lds[0][0][wm][0];
        const unsigned short* B0 = &lds[0][1][wn >> 1][0];
        const unsigned short* A1 = &lds[1][0][wm][0];
        const unsigned short* B1 = &lds[1][1][wn >> 1][0];
        const bool more = (tt + 2 < NT);          // NT even: covers t+2 and t+3
        const int kA1 = (tt + 1) * BK;
        const int kN2 = (tt + 2) * BK;
        const int kN3 = (tt + 3) * BK;

        // ---- tile t (buf0), phases p0-p3 ----
        PHASE(A0, 0, 1, B0, { stageA(1, 0, kA1); }, {});
        PHASE(A0, 1, 0, B0, { stageA(1, 1, kA1); }, {});
        PHASE(A0, 2, 0, B0, { if (more) stageB(0, 0, kN2); }, {});
        PHASE(A0, 3, 0, B0, { if (more) stageB(0, 1, kN2); },
              { if (more) { asm volatile("s_waitcnt vmcnt(4)" ::: "memory"); }
                else      { asm volatile("s_waitcnt vmcnt(0)" ::: "memory"); } });

        // ---- tile t+1 (buf1), phases p4-p7 ----
        PHASE(A1, 0, 1, B1, { if (more) stageA(0, 0, kN2); }, {});
        PHASE(A1, 1, 0, B1, { if (more) stageA(0, 1, kN2); }, {});
        PHASE(A1, 2, 0, B1, { if (more) stageB(1, 0, kN3); }, {});
        PHASE(A1, 3, 0, B1, { if (more) stageB(1, 1, kN3); },
              { if (more) { asm volatile("s_waitcnt vmcnt(4)" ::: "memory"); }
                else      { asm volatile("s_waitcnt vmcnt(0)" ::: "memory"); } });
    }

    // ---- epilogue: C/D layout col=lane&15, row=(lane>>4)*4+reg; NT stores ----
    const size_t crow0 = (size_t)tm * BM + wm * 128 + l4 * 4;
    const int ccol0 = tn * BN + wn * 64 + l15;
#pragma unroll
    for (int i = 0; i < 8; ++i) {
#pragma unroll
        for (int j = 0; j < 4; ++j) {
            float* cp = C + (crow0 + i * 16) * N_DIM + ccol0 + j * 16;
#pragma unroll
            for (int r = 0; r < 4; ++r)
                __builtin_nontemporal_store(acc[i][j][r], cp + (size_t)r * N_DIM);
        }
    }
}

extern "C" void kernel_launch(void* const* d_in, const int* in_sizes, int n_in,
                              void* d_out, int out_size, void* d_ws, size_t ws_size,
                              hipStream_t stream) {
    const float* x = (const float*)d_in[0];       // [4,2048,4096] fp32
    const float* w = (const float*)d_in[1];       // [11008,4096] fp32
    float* out = (float*)d_out;                   // [4,2048,11008] fp32

    unsigned short* xb = (unsigned short*)d_ws;                                        // 64 MiB
    unsigned short* weff = (unsigned short*)((char*)d_ws + (size_t)M_DIM * K_DIM * 2); // 86 MiB

    cast_x_kernel<<<(M_DIM * K_DIM / 8) / 256, 256, 0, stream>>>(x, xb);
    binarize_w_kernel<<<(N_DIM * K_DIM / 4) / 256, 256, 0, stream>>>(w, weff);
    gemm_bin_kernel<<<NWG, 512, 0, stream>>>(xb, weff, out);
}